// Round 13
// baseline (289.242 us; speedup 1.0000x reference)
//
#include <hip/hip_runtime.h>
#include <hip/hip_bf16.h>

// RNN: B=1024, T=512, E=64, H=128, OUT=2, VOCAB=4411
// R13 = R12 i8 datapath, re-cut to 4 waves + integer C-seeding.
//  R12 post-mortem: 785 cyc/step INVARIANT across bf16/f16/i8 and tanh
//  variants -> step is dominated by fixed cost (barrier + lgkm drain +
//  ds_read latency) + per-wave issue, not pipe throughput. So:
//   1. 4 waves x 32 j (halves barrier skew / per-SIMD issue vs 8 waves;
//      with i8 traffic + cheap tanh the R8-era reasons for 8 waves are gone).
//   2. pe table stored as i32 (scale S = 127^2*sqrt(128)): x_proj enters the
//      MFMA C operand, exact i32 accumulation. Per-value epilogue is just
//      cvt + mul(k*inv folded) + exp2 + add + rcp + fma + cvt (tanh127).
//   3. Per wave-step: 2 b128 B-reads, 2x(2-chained) K=64 i8 MFMAs seeded
//      with xpi, 8 tanh127, 2 b32 writes. Skeleton (lgkm-only barrier,
//      B-frag-order LDS, token staging, depth-2 xpi pipeline) unchanged.
// i8 fragment maps: A[m][k]: m=L&15, k=(L>>4)*16+s; B[k][n]: n=L&15, same k;
// D[m][n]: n=L&15, m=(L>>4)*4+reg (i32).

constexpr int Bc    = 1024;
constexpr int Tc    = 512;
constexpr int Ec    = 64;
constexpr int Hc    = 128;
constexpr int OUTc  = 2;
constexpr int VOCAB = 4411;

typedef int   intx4  __attribute__((ext_vector_type(4)));

// Scale: z_true = acc / S, S = 127*127*sqrt(128)
#define S_SCALE 182458.08595437f
#define KINV    (2.8853900817779268f / S_SCALE)   // folds tanh's log2(e)*2 and 1/S

// Workgroup barrier draining ONLY lgkmcnt (LDS); global loads stay in flight.
#define LGKM_BARRIER() asm volatile("s_waitcnt lgkmcnt(0)\n\ts_barrier" ::: "memory")

__device__ __forceinline__ int pack4i8(int i0, int i1, int i2, int i3) {
    return (i0 & 255) | ((i1 & 255) << 8) | ((i2 & 255) << 16) | ((i3 & 255) << 24);
}
// tanh(acc/S)*127 = 127 - 254*rcp(exp2(KINV*acc)+1); exact at saturation.
__device__ __forceinline__ int tanh127i(float accf) {
    const float e = __builtin_amdgcn_exp2f(KINV * accf);
    const float r = __builtin_amdgcn_rcpf(e + 1.0f);
    return __float2int_rn(fmaf(-254.0f, r, 127.0f));
}

// ------------- Kernel 1: pei[v][j] = round(S * (emb[v].W_ih[j] + biases)) ----
constexpr int PV = 16;
__global__ __launch_bounds__(256) void pe_kernel(
    const float* __restrict__ emb, const float* __restrict__ W_ih,
    const float* __restrict__ b_ih, const float* __restrict__ b_hh,
    int* __restrict__ pei)
{
    const int tid  = threadIdx.x;
    const int j    = tid & 127;
    const int half = tid >> 7;
    const int v0   = blockIdx.x * PV;

    __shared__ float es[PV * Ec];       // 4 KB
    for (int i = tid; i < PV * Ec / 4; i += 256) {
        const int flat = i * 4, vv = flat >> 6;
        if (v0 + vv < VOCAB)
            *(float4*)&es[flat] = *(const float4*)(emb + (long)(v0 + vv) * Ec + (flat & 63));
    }

    float4 wr[Ec / 4];
#pragma unroll
    for (int e = 0; e < Ec / 4; ++e)
        wr[e] = *(const float4*)(W_ih + j * Ec + e * 4);
    const float bias = b_ih[j] + b_hh[j];

    __syncthreads();

    const int vbeg = half * (PV / 2), vend = vbeg + PV / 2;
    for (int vv = vbeg; vv < vend; ++vv) {
        if (v0 + vv >= VOCAB) break;
        const float* er = &es[vv * Ec];
        float a0 = bias, a1 = 0.f, a2 = 0.f, a3 = 0.f;
#pragma unroll
        for (int e = 0; e < Ec / 4; ++e) {
            const float4 E = *(const float4*)(er + 4 * e);
            a0 = fmaf(E.x, wr[e].x, a0);
            a1 = fmaf(E.y, wr[e].y, a1);
            a2 = fmaf(E.z, wr[e].z, a2);
            a3 = fmaf(E.w, wr[e].w, a3);
        }
        pei[(long)(v0 + vv) * Hc + j] =
            __float2int_rn(((a0 + a1) + (a2 + a3)) * S_SCALE);
    }
}

// ------------- Kernel 2: i8 MFMA recurrence, 4 waves, C-seeded ---------------
constexpr int HT_BUF     = 2048;  // BYTES per h buffer (2 K-tiles x 1024)
constexpr int TOK_STRIDE = 513;   // ints per b-row

__global__ __attribute__((amdgpu_flat_work_group_size(256, 256)))
void rnn_mfma(
    const int*   __restrict__ inputs,  // [B, T]
    const int*   __restrict__ pei,     // [VOCAB, H] scaled i32
    const float* __restrict__ W_hh,    // [H, H]
    const float* __restrict__ W_lin,   // [OUT, H]
    const float* __restrict__ b_lin,   // [OUT]
    float* __restrict__ out)           // [B, OUT]
{
    const int tid = threadIdx.x;
    const int w   = tid >> 6;      // wave 0..3 -> j in [32w, 32w+32)
    const int L   = tid & 63;
    const int q   = L >> 4;        // 0..3
    const int b   = L & 15;        // batch sub-row / MFMA col
    const int blk = blockIdx.x;
    const int jb  = w * 32;

    __shared__ __align__(16) signed char HT[2 * HT_BUF];
    __shared__ int toks[16 * TOK_STRIDE];

    // Stage 16 token rows (32 KB) into LDS, coalesced.
    {
        const int base = blk * 16 * Tc;
        for (int i = tid; i < 16 * Tc / 4; i += 256) {
            const int4 v4 = *(const int4*)(inputs + base + i * 4);
            const int bb = (i * 4) >> 9, t0 = (i * 4) & 511;
            int* dst = &toks[bb * TOK_STRIDE + t0];
            dst[0] = v4.x; dst[1] = v4.y; dst[2] = v4.z; dst[3] = v4.w;
        }
    }
    // Zero h buffer 0 (h_0 = 0): 512 dwords.
    {
        unsigned int* z = (unsigned int*)HT;
        for (int i = tid; i < HT_BUF / 4; i += 256) z[i] = 0u;
    }

    // Static A fragments: W_hh rows [jb+mt*16, +16) quantized to i8.
    // s_W = 127*sqrt(128); |W| <= 1/sqrt(128) -> |Wq| <= 127 exactly.
    const float s_W = 127.0f * 11.313708498984761f;
    intx4 wfrag[2][2];   // [mt][kt]
#pragma unroll
    for (int mt = 0; mt < 2; ++mt) {
        const float* wr = W_hh + (jb + mt * 16 + b) * Hc;   // A row m = L&15
#pragma unroll
        for (int kt = 0; kt < 2; ++kt) {
#pragma unroll
            for (int d = 0; d < 4; ++d) {
                const float4 v = *(const float4*)(wr + kt * 64 + q * 16 + d * 4);
                wfrag[mt][kt][d] = pack4i8(__float2int_rn(v.x * s_W),
                                           __float2int_rn(v.y * s_W),
                                           __float2int_rn(v.z * s_W),
                                           __float2int_rn(v.w * s_W));
            }
        }
    }
    asm volatile("" : "+v"(wfrag[0][0]), "+v"(wfrag[0][1]),
                      "+v"(wfrag[1][0]), "+v"(wfrag[1][1]));

    signed char* const ht0 = HT;
    signed char* const ht1 = HT + HT_BUF;
    const int rd_base = L * 16;         // + kt*1024: lane-sequential b128
    // Write: lane owns h[j0..j0+3][b] per mt, j0 = jb + mt*16 + q*4.
    // byte(k,n) = (k>>6)*1024 + (((k>>4)&3)*16 + n)*16 + (k&15)
    int wr_off[2];
#pragma unroll
    for (int mt = 0; mt < 2; ++mt) {
        const int j0 = jb + mt * 16 + q * 4;
        wr_off[mt] = ((j0 >> 6) << 10) + ((((j0 >> 4) & 3) * 16 + b) << 4) + (j0 & 15);
    }
    const int xp_off = jb + q * 4;      // pei column base for this lane (mt=0)

    const int* tr = &toks[b * TOK_STRIDE];

    __syncthreads();   // tokens + zeroed h0 visible (one-time full drain)

    // Prologue: xpi for t=0 and t=1 (two int4 per step: mt=0, mt=1).
    int4 xpc0, xpc1, xpn0, xpn1;
    {
        const int t0 = tr[0], t1 = tr[1];
        xpc0 = *(const int4*)(pei + (long)t0 * Hc + xp_off);
        xpc1 = *(const int4*)(pei + (long)t0 * Hc + xp_off + 16);
        xpn0 = *(const int4*)(pei + (long)t1 * Hc + xp_off);
        xpn1 = *(const int4*)(pei + (long)t1 * Hc + xp_off + 16);
    }

    for (int t = 0; t < Tc; ++t) {
        signed char* const rbuf = (t & 1) ? ht1 : ht0;
        signed char* const wbuf = (t & 1) ? ht0 : ht1;

        // B fragments: h i8, 2 x b128 lane-sequential (conflict-free).
        intx4 bfrag[2];
#pragma unroll
        for (int kt = 0; kt < 2; ++kt)
            bfrag[kt] = *(const intx4*)(rbuf + kt * 1024 + rd_base);

        // Prefetch pei rows for t+2 (stay in flight across the lgkm barrier).
        int4 xf0, xf1;
        {
            const int tk = tr[(t + 2 < Tc) ? (t + 2) : (Tc - 1)];
            const int* p = pei + (long)tk * Hc + xp_off;
            xf0 = *(const int4*)(p);
            xf1 = *(const int4*)(p + 16);
        }

        // Per mt: 2 chained K=64 i8 MFMAs, C seeded with scaled x_proj (exact).
        const intx4 c0 = (intx4){xpc0.x, xpc0.y, xpc0.z, xpc0.w};
        const intx4 c1 = (intx4){xpc1.x, xpc1.y, xpc1.z, xpc1.w};
        intx4 a0 = __builtin_amdgcn_mfma_i32_16x16x64_i8(wfrag[0][0], bfrag[0], c0, 0, 0, 0);
        intx4 a1 = __builtin_amdgcn_mfma_i32_16x16x64_i8(wfrag[1][0], bfrag[0], c1, 0, 0, 0);
        a0 = __builtin_amdgcn_mfma_i32_16x16x64_i8(wfrag[0][1], bfrag[1], a0, 0, 0, 0);
        a1 = __builtin_amdgcn_mfma_i32_16x16x64_i8(wfrag[1][1], bfrag[1], a1, 0, 0, 0);

        // tanh*127 -> i8 -> one b32 LDS write per mt.
        *(int*)(wbuf + wr_off[0]) = pack4i8(tanh127i((float)a0[0]),
                                            tanh127i((float)a0[1]),
                                            tanh127i((float)a0[2]),
                                            tanh127i((float)a0[3]));
        *(int*)(wbuf + wr_off[1]) = pack4i8(tanh127i((float)a1[0]),
                                            tanh127i((float)a1[1]),
                                            tanh127i((float)a1[2]),
                                            tanh127i((float)a1[3]));

        LGKM_BARRIER();   // drains LDS only; pei prefetch stays outstanding

        xpc0 = xpn0; xpc1 = xpn1;
        xpn0 = xf0;  xpn1 = xf1;
    }

    // Final h is in ht0 (t=511 wrote ht0), i8 B-frag order. Linear head.
    if (tid < 16 * OUTc) {
        const int bb = tid >> 1, o = tid & 1;
        float s = b_lin[o];
        const float* wl = W_lin + o * Hc;
        const float ih = 1.0f / 127.0f;
#pragma unroll 8
        for (int k = 0; k < Hc; ++k) {
            const int off = ((k >> 6) << 10) + ((((k >> 4) & 3) * 16 + bb) << 4) + (k & 15);
            s = fmaf((float)ht0[off] * ih, wl[k], s);
        }
        out[(blk * 16 + bb) * OUTc + o] = s;
    }
}

extern "C" void kernel_launch(void* const* d_in, const int* in_sizes, int n_in,
                              void* d_out, int out_size, void* d_ws, size_t ws_size,
                              hipStream_t stream) {
    const int*   inputs    = (const int*)d_in[0];
    const float* emb_table = (const float*)d_in[1];
    const float* W_ih      = (const float*)d_in[2];
    const float* W_hh      = (const float*)d_in[3];
    const float* b_ih      = (const float*)d_in[4];
    const float* b_hh      = (const float*)d_in[5];
    const float* W_lin     = (const float*)d_in[6];
    const float* b_lin     = (const float*)d_in[7];
    float* out = (float*)d_out;

    int* pei = (int*)d_ws;  // VOCAB*H*4 = 2.26 MB
    pe_kernel<<<(VOCAB + PV - 1) / PV, 256, 0, stream>>>(emb_table, W_ih, b_ih, b_hh, pei);
    rnn_mfma<<<Bc / 16, 256, 0, stream>>>(inputs, pei, W_hh, W_lin, b_lin, out);
}

// Round 14
// 264.475 us; speedup vs baseline: 1.0936x; 1.0936x over previous
//
#include <hip/hip_runtime.h>
#include <hip/hip_bf16.h>

// RNN: B=1024, T=512, E=64, H=128, OUT=2, VOCAB=4411
// R14 = R12's recurrence BYTE-IDENTICAL (166.7us; 785cyc/step invariant across
// bf16/f16/i8 datapaths -> latency/issue floor at 8 waves) + pe table folded
// into the SAME kernel behind a software grid barrier:
//  - 64 blocks, each computes a 69-vocab-row slice of pe (f32, in d_ws):
//    ~1150 FMA/thread, emb rows via wave-broadcast global reads (~1-2us).
//  - Grid barrier: per-block flag in the TAIL of d_out (harness re-poisons
//    d_out to 0xAA each launch; flags are overwritten by real outputs only
//    after every block passed the barrier -> race-free). Device-scope
//    atomics + __threadfence for cross-XCD visibility (G16).
//  - 64 blocks <= 256 CUs: all co-resident, no deadlock.
// Removes the pe_kernel dispatch (~13us of the 238.6 total).
// R13 post-mortem locked in: 8 waves optimal (4-wave = 1019cyc/step); never
// seed MFMA C from vmem loads; never restructure the K-loop skeleton.

constexpr int Bc    = 1024;
constexpr int Tc    = 512;
constexpr int Ec    = 64;
constexpr int Hc    = 128;
constexpr int OUTc  = 2;
constexpr int VOCAB = 4411;
constexpr int NBLK  = Bc / 16;     // 64 recurrence blocks
constexpr int PVB   = (VOCAB + NBLK - 1) / NBLK;  // 69 vocab rows per block

typedef int intx4 __attribute__((ext_vector_type(4)));

// Workgroup barrier draining ONLY lgkmcnt (LDS); global loads stay in flight.
#define LGKM_BARRIER() asm volatile("s_waitcnt lgkmcnt(0)\n\ts_barrier" ::: "memory")

__device__ __forceinline__ int pack4i8(int i0, int i1, int i2, int i3) {
    return (i0 & 255) | ((i1 & 255) << 8) | ((i2 & 255) << 16) | ((i3 & 255) << 24);
}
// tanh(z)*127 = 127 - 254*rcp(exp2(2.88539*z)+1); exact at saturation.
__device__ __forceinline__ int tanh127(float z) {
    const float e = __builtin_amdgcn_exp2f(2.8853900817779268f * z);
    const float r = __builtin_amdgcn_rcpf(e + 1.0f);
    return __float2int_rn(fmaf(-254.0f, r, 127.0f));
}

constexpr int HT_BUF     = 2048;  // BYTES per h buffer (2 K-tiles x 1024)
constexpr int TOK_STRIDE = 513;   // ints per b-row

__global__ __attribute__((amdgpu_flat_work_group_size(512, 512)))
void rnn_mfma(
    const int*   __restrict__ inputs,  // [B, T]
    const float* __restrict__ emb,     // [VOCAB, E]
    const float* __restrict__ W_ih,    // [H, E]
    const float* __restrict__ b_ih,    // [H]
    const float* __restrict__ b_hh,    // [H]
    float*       __restrict__ pe,      // [VOCAB, H] workspace (d_ws)
    const float* __restrict__ W_hh,    // [H, H]
    const float* __restrict__ W_lin,   // [OUT, H]
    const float* __restrict__ b_lin,   // [OUT]
    float* __restrict__ out)           // [B, OUT]; last 64 ints = barrier flags
{
    const int tid = threadIdx.x;
    const int w   = tid >> 6;      // wave 0..7 -> j in [16w, 16w+16)
    const int L   = tid & 63;
    const int q   = L >> 4;        // 0..3
    const int b   = L & 15;        // batch sub-row / MFMA col
    const int blk = blockIdx.x;
    const int jb  = w * 16;

    int* const flags = (int*)out + Bc * OUTc - NBLK;   // tail of d_out

    __shared__ __align__(16) signed char HT[2 * HT_BUF];
    __shared__ int toks[16 * TOK_STRIDE];

    // ---- Phase 0a: stage 16 token rows (32 KB) into LDS, coalesced. ----
    {
        const int base = blk * 16 * Tc;
        for (int i = tid; i < 16 * Tc / 4; i += 512) {
            const int4 v4 = *(const int4*)(inputs + base + i * 4);
            const int bb = (i * 4) >> 9, t0 = (i * 4) & 511;
            int* dst = &toks[bb * TOK_STRIDE + t0];
            dst[0] = v4.x; dst[1] = v4.y; dst[2] = v4.z; dst[3] = v4.w;
        }
    }
    // Zero h buffer 0 (h_0 = 0): 512 dwords.
    {
        unsigned int* z = (unsigned int*)HT;
        for (int i = tid; i < HT_BUF / 4; i += 512) z[i] = 0u;
    }

    // ---- Phase 0b: this block's pe slice: rows [blk*69, +69). ----
    // thread = (g = tid>>7 in 0..3, j = tid&127); g handles rows v0+g+4i.
    {
        const int j  = tid & 127;
        const int g  = tid >> 7;
        const int v0 = blk * PVB;

        float4 wr[Ec / 4];
#pragma unroll
        for (int e = 0; e < Ec / 4; ++e)
            wr[e] = *(const float4*)(W_ih + j * Ec + e * 4);
        const float bias = b_ih[j] + b_hh[j];

        for (int v = v0 + g; v < v0 + PVB && v < VOCAB; v += 4) {
            const float* er = emb + (long)v * Ec;   // wave-broadcast reads
            float a0 = bias, a1 = 0.f, a2 = 0.f, a3 = 0.f;
#pragma unroll
            for (int e = 0; e < Ec / 4; ++e) {
                const float4 E = *(const float4*)(er + 4 * e);
                a0 = fmaf(E.x, wr[e].x, a0);
                a1 = fmaf(E.y, wr[e].y, a1);
                a2 = fmaf(E.z, wr[e].z, a2);
                a3 = fmaf(E.w, wr[e].w, a3);
            }
            pe[(long)v * Hc + j] = (a0 + a1) + (a2 + a3);
        }
    }

    // ---- Grid barrier arrive: pe stores done -> flag this block. ----
    __syncthreads();                     // drains vmcnt: pe stores complete
    if (tid == 0) {
        __threadfence();                 // release: device-visible (cross-XCD)
        __hip_atomic_store(&flags[blk], 1, __ATOMIC_RELEASE,
                           __HIP_MEMORY_SCOPE_AGENT);
    }

    // ---- Static A fragments (independent of pe; overlaps the wait). ----
    // W_hh rows [jb, jb+16) quantized to i8; s_W = 127*sqrt(128) (|Wq|<=127).
    const float s_W  = 127.0f * 11.313708498984761f;
    const float invs = 1.0f / (127.0f * 127.0f * 11.313708498984761f);
    intx4 wfrag[2];
    {
        const float* wr = W_hh + (jb + b) * Hc;            // A row m = L&15
#pragma unroll
        for (int kt = 0; kt < 2; ++kt) {
#pragma unroll
            for (int d = 0; d < 4; ++d) {
                const float4 v = *(const float4*)(wr + kt * 64 + q * 16 + d * 4);
                wfrag[kt][d] = pack4i8(__float2int_rn(v.x * s_W),
                                       __float2int_rn(v.y * s_W),
                                       __float2int_rn(v.z * s_W),
                                       __float2int_rn(v.w * s_W));
            }
        }
    }
    asm volatile("" : "+v"(wfrag[0]), "+v"(wfrag[1]));

    signed char* const ht0 = HT;
    signed char* const ht1 = HT + HT_BUF;
    const int rd_base = L * 16;         // + kt*1024: lane-sequential b128
    // Write: lane owns h[j0..j0+3][b], j0 = jb+q*4; byte (k,n) lives at
    // (k>>6)*1024 + (((k>>4)&3)*16 + n)*16 + (k&15).
    const int wr_off = ((w >> 2) << 10) + (((w & 3) * 16 + b) << 4) + q * 4;
    const int xp_off = jb + q * 4;      // pe column base for this lane

    const int* tr = &toks[b * TOK_STRIDE];
    const intx4 zac = (intx4){0, 0, 0, 0};

    // ---- Grid barrier wait: all 64 pe slices visible. ----
    if (tid == 0) {
        int ready = 0;
        while (ready != NBLK) {
            ready = 0;
            for (int i = 0; i < NBLK; ++i)
                ready += (__hip_atomic_load(&flags[i], __ATOMIC_RELAXED,
                                            __HIP_MEMORY_SCOPE_AGENT) == 1);
            if (ready != NBLK) __builtin_amdgcn_s_sleep(8);
        }
        __threadfence();                 // acquire: invalidate for pe reads
    }
    __syncthreads();   // tokens + zeroed h0 + barrier result visible

    // Prologue: xp for t=0 and t=1.
    float4 xpc, xpn;
    {
        const int t0 = tr[0], t1 = tr[1];
        xpc = *(const float4*)(pe + (long)t0 * Hc + xp_off);
        xpn = *(const float4*)(pe + (long)t1 * Hc + xp_off);
    }

    for (int t = 0; t < Tc; ++t) {
        signed char* const rbuf = (t & 1) ? ht1 : ht0;
        signed char* const wbuf = (t & 1) ? ht0 : ht1;

        // B fragments: h i8, 2 x b128 lane-sequential (conflict-free).
        intx4 bfrag[2];
#pragma unroll
        for (int kt = 0; kt < 2; ++kt)
            bfrag[kt] = *(const intx4*)(rbuf + kt * 1024 + rd_base);

        // Prefetch pe row for t+2 (stays in flight across the lgkm barrier).
        float4 xp2;
        {
            const int tk = tr[(t + 2 < Tc) ? (t + 2) : (Tc - 1)];
            xp2 = *(const float4*)(pe + (long)tk * Hc + xp_off);
        }

        // 2 chained i8 MFMAs (K=64 each), exact i32 accumulation.
        intx4 acc = __builtin_amdgcn_mfma_i32_16x16x64_i8(wfrag[0], bfrag[0], zac, 0, 0, 0);
        acc = __builtin_amdgcn_mfma_i32_16x16x64_i8(wfrag[1], bfrag[1], acc, 0, 0, 0);

        // z = acc*inv + xp -> tanh*127 -> i8 -> one b32 LDS write.
        const int i0 = tanh127(fmaf((float)acc[0], invs, xpc.x));
        const int i1 = tanh127(fmaf((float)acc[1], invs, xpc.y));
        const int i2 = tanh127(fmaf((float)acc[2], invs, xpc.z));
        const int i3 = tanh127(fmaf((float)acc[3], invs, xpc.w));
        *(int*)(wbuf + wr_off) = pack4i8(i0, i1, i2, i3);

        LGKM_BARRIER();   // drains LDS only; pe prefetch stays outstanding

        xpc = xpn;
        xpn = xp2;
    }

    // Final h is in ht0 (t=511 wrote ht0), i8 B-frag order. Linear head.
    // (Writes overwrite the flag region only after every block passed the
    //  grid barrier ~160us earlier -- race-free.)
    if (tid < 16 * OUTc) {
        const int bb = tid >> 1, o = tid & 1;
        float s = b_lin[o];
        const float* wl = W_lin + o * Hc;
        const float ih = 1.0f / 127.0f;
#pragma unroll 8
        for (int k = 0; k < Hc; ++k) {
            const int off = ((k >> 6) << 10) + ((((k >> 4) & 3) * 16 + bb) << 4) + (k & 15);
            s = fmaf((float)ht0[off] * ih, wl[k], s);
        }
        out[(blk * 16 + bb) * OUTc + o] = s;
    }
}

extern "C" void kernel_launch(void* const* d_in, const int* in_sizes, int n_in,
                              void* d_out, int out_size, void* d_ws, size_t ws_size,
                              hipStream_t stream) {
    const int*   inputs    = (const int*)d_in[0];
    const float* emb_table = (const float*)d_in[1];
    const float* W_ih      = (const float*)d_in[2];
    const float* W_hh      = (const float*)d_in[3];
    const float* b_ih      = (const float*)d_in[4];
    const float* b_hh      = (const float*)d_in[5];
    const float* W_lin     = (const float*)d_in[6];
    const float* b_lin     = (const float*)d_in[7];
    float* out = (float*)d_out;

    float* pe = (float*)d_ws;  // VOCAB*H*4 = 2.26 MB
    rnn_mfma<<<NBLK, 512, 0, stream>>>(inputs, emb_table, W_ih, b_ih, b_hh,
                                       pe, W_hh, W_lin, b_lin, out);
}

// Round 15
// 238.072 us; speedup vs baseline: 1.2149x; 1.1109x over previous
//
#include <hip/hip_runtime.h>
#include <hip/hip_bf16.h>

// RNN: B=1024, T=512, E=64, H=128, OUT=2, VOCAB=4411
// R15 = EXACT REVERT to R12 (best measured: 238.6us total; rnn 166.7us).
// Session conclusions baked in:
//  - 785 cyc/step is invariant across bf16/f16/i8, tanh impls, LDS layouts,
//    wave counts (8 optimal), C-seeding, pe-fusion -> latency/exchange floor:
//    barrier + convoyed ds_read + MFMA/tanh chain + ds_write + lgkm drain.
//  - lgkm-only barrier (global prefetch never drained) is the key enabler.
//  - i8 datapath: h x127 (quant step == bf16 spacing near 1), W_hh with
//    exact-bound scale 127*sqrt(128), i32 MFMA accumulation exact.
//  - Fixed ~59us bench-vs-kernel overhead is harness-side (confirmed x3).
// Never: restructure the K-loop, seed MFMA C from vmem loads, use <8 waves.

constexpr int Bc    = 1024;
constexpr int Tc    = 512;
constexpr int Ec    = 64;
constexpr int Hc    = 128;
constexpr int OUTc  = 2;
constexpr int VOCAB = 4411;

typedef int   intx4  __attribute__((ext_vector_type(4)));
typedef float floatx4 __attribute__((ext_vector_type(4)));

// Workgroup barrier draining ONLY lgkmcnt (LDS); global loads stay in flight.
#define LGKM_BARRIER() asm volatile("s_waitcnt lgkmcnt(0)\n\ts_barrier" ::: "memory")

__device__ __forceinline__ int pack4i8(int i0, int i1, int i2, int i3) {
    return (i0 & 255) | ((i1 & 255) << 8) | ((i2 & 255) << 16) | ((i3 & 255) << 24);
}
// tanh(z)*127 = 127 - 254*rcp(exp2(2.88539*z)+1); exact at saturation.
__device__ __forceinline__ int tanh127(float z) {
    const float e = __builtin_amdgcn_exp2f(2.8853900817779268f * z);
    const float r = __builtin_amdgcn_rcpf(e + 1.0f);
    return __float2int_rn(fmaf(-254.0f, r, 127.0f));
}

// ---------------- Kernel 1: pe[v][j] = emb[v].W_ih[j] + b_ih[j] + b_hh[j] ----
constexpr int PV = 16;
__global__ __launch_bounds__(256) void pe_kernel(
    const float* __restrict__ emb, const float* __restrict__ W_ih,
    const float* __restrict__ b_ih, const float* __restrict__ b_hh,
    float* __restrict__ pe)
{
    const int tid  = threadIdx.x;
    const int j    = tid & 127;
    const int half = tid >> 7;
    const int v0   = blockIdx.x * PV;

    __shared__ float es[PV * Ec];       // 4 KB
    for (int i = tid; i < PV * Ec / 4; i += 256) {
        const int flat = i * 4, vv = flat >> 6;
        if (v0 + vv < VOCAB)
            *(float4*)&es[flat] = *(const float4*)(emb + (long)(v0 + vv) * Ec + (flat & 63));
    }

    float4 wr[Ec / 4];
#pragma unroll
    for (int e = 0; e < Ec / 4; ++e)
        wr[e] = *(const float4*)(W_ih + j * Ec + e * 4);
    const float bias = b_ih[j] + b_hh[j];

    __syncthreads();

    const int vbeg = half * (PV / 2), vend = vbeg + PV / 2;
    for (int vv = vbeg; vv < vend; ++vv) {
        if (v0 + vv >= VOCAB) break;
        const float* er = &es[vv * Ec];
        float a0 = bias, a1 = 0.f, a2 = 0.f, a3 = 0.f;
#pragma unroll
        for (int e = 0; e < Ec / 4; ++e) {
            const float4 E = *(const float4*)(er + 4 * e);
            a0 = fmaf(E.x, wr[e].x, a0);
            a1 = fmaf(E.y, wr[e].y, a1);
            a2 = fmaf(E.z, wr[e].z, a2);
            a3 = fmaf(E.w, wr[e].w, a3);
        }
        pe[(long)(v0 + vv) * Hc + j] = (a0 + a1) + (a2 + a3);
    }
}

// ---------------- Kernel 2: i8 MFMA recurrence (R10 skeleton) ----------------
constexpr int HT_BUF     = 2048;  // BYTES per h buffer (2 K-tiles x 1024)
constexpr int TOK_STRIDE = 513;   // ints per b-row

__global__ __attribute__((amdgpu_flat_work_group_size(512, 512)))
void rnn_mfma(
    const int*   __restrict__ inputs,  // [B, T]
    const float* __restrict__ pe,      // [VOCAB, H]
    const float* __restrict__ W_hh,    // [H, H]
    const float* __restrict__ W_lin,   // [OUT, H]
    const float* __restrict__ b_lin,   // [OUT]
    float* __restrict__ out)           // [B, OUT]
{
    const int tid = threadIdx.x;
    const int w   = tid >> 6;      // wave 0..7 -> j in [16w, 16w+16)
    const int L   = tid & 63;
    const int q   = L >> 4;        // 0..3
    const int b   = L & 15;        // batch sub-row / MFMA col
    const int blk = blockIdx.x;
    const int jb  = w * 16;

    __shared__ __align__(16) signed char HT[2 * HT_BUF];
    __shared__ int toks[16 * TOK_STRIDE];

    // Stage 16 token rows (32 KB) into LDS, coalesced.
    {
        const int base = blk * 16 * Tc;
        for (int i = tid; i < 16 * Tc / 4; i += 512) {
            const int4 v4 = *(const int4*)(inputs + base + i * 4);
            const int bb = (i * 4) >> 9, t0 = (i * 4) & 511;
            int* dst = &toks[bb * TOK_STRIDE + t0];
            dst[0] = v4.x; dst[1] = v4.y; dst[2] = v4.z; dst[3] = v4.w;
        }
    }
    // Zero h buffer 0 (h_0 = 0): 512 dwords.
    {
        unsigned int* z = (unsigned int*)HT;
        for (int i = tid; i < HT_BUF / 4; i += 512) z[i] = 0u;
    }

    // Static A fragments: W_hh rows [jb, jb+16) quantized to i8.
    // s_W = 127*sqrt(128); |W| <= 1/sqrt(128) -> |Wq| <= 127 exactly.
    const float s_W  = 127.0f * 11.313708498984761f;
    const float invs = 1.0f / (127.0f * 127.0f * 11.313708498984761f);
    intx4 wfrag[2];
    {
        const float* wr = W_hh + (jb + b) * Hc;            // A row m = L&15
#pragma unroll
        for (int kt = 0; kt < 2; ++kt) {
#pragma unroll
            for (int d = 0; d < 4; ++d) {
                const float4 v = *(const float4*)(wr + kt * 64 + q * 16 + d * 4);
                wfrag[kt][d] = pack4i8(__float2int_rn(v.x * s_W),
                                       __float2int_rn(v.y * s_W),
                                       __float2int_rn(v.z * s_W),
                                       __float2int_rn(v.w * s_W));
            }
        }
    }
    asm volatile("" : "+v"(wfrag[0]), "+v"(wfrag[1]));

    signed char* const ht0 = HT;
    signed char* const ht1 = HT + HT_BUF;
    const int rd_base = L * 16;         // + kt*1024: lane-sequential b128
    // Write: lane owns h[j0..j0+3][b], j0 = jb+q*4; byte (k,n) lives at
    // (k>>6)*1024 + (((k>>4)&3)*16 + n)*16 + (k&15).
    const int wr_off = ((w >> 2) << 10) + (((w & 3) * 16 + b) << 4) + q * 4;
    const int xp_off = jb + q * 4;      // pe column base for this lane

    const int* tr = &toks[b * TOK_STRIDE];
    const intx4 zac = (intx4){0, 0, 0, 0};

    __syncthreads();   // tokens + zeroed h0 visible (one-time full drain)

    // Prologue: xp for t=0 and t=1.
    float4 xpc, xpn;
    {
        const int t0 = tr[0], t1 = tr[1];
        xpc = *(const float4*)(pe + (long)t0 * Hc + xp_off);
        xpn = *(const float4*)(pe + (long)t1 * Hc + xp_off);
    }

    for (int t = 0; t < Tc; ++t) {
        signed char* const rbuf = (t & 1) ? ht1 : ht0;
        signed char* const wbuf = (t & 1) ? ht0 : ht1;

        // B fragments: h i8, 2 x b128 lane-sequential (conflict-free).
        intx4 bfrag[2];
#pragma unroll
        for (int kt = 0; kt < 2; ++kt)
            bfrag[kt] = *(const intx4*)(rbuf + kt * 1024 + rd_base);

        // Prefetch pe row for t+2 (stays in flight across the lgkm barrier).
        float4 xp2;
        {
            const int tk = tr[(t + 2 < Tc) ? (t + 2) : (Tc - 1)];
            xp2 = *(const float4*)(pe + (long)tk * Hc + xp_off);
        }

        // 2 chained i8 MFMAs (K=64 each), exact i32 accumulation.
        intx4 acc = __builtin_amdgcn_mfma_i32_16x16x64_i8(wfrag[0], bfrag[0], zac, 0, 0, 0);
        acc = __builtin_amdgcn_mfma_i32_16x16x64_i8(wfrag[1], bfrag[1], acc, 0, 0, 0);

        // z = acc*inv + xp -> tanh*127 -> i8 -> one b32 LDS write.
        const int i0 = tanh127(fmaf((float)acc[0], invs, xpc.x));
        const int i1 = tanh127(fmaf((float)acc[1], invs, xpc.y));
        const int i2 = tanh127(fmaf((float)acc[2], invs, xpc.z));
        const int i3 = tanh127(fmaf((float)acc[3], invs, xpc.w));
        *(int*)(wbuf + wr_off) = pack4i8(i0, i1, i2, i3);

        LGKM_BARRIER();   // drains LDS only; pe prefetch stays outstanding

        xpc = xpn;
        xpn = xp2;
    }

    // Final h is in ht0 (t=511 wrote ht0), i8 B-frag order. Linear head.
    if (tid < 16 * OUTc) {
        const int bb = tid >> 1, o = tid & 1;
        float s = b_lin[o];
        const float* wl = W_lin + o * Hc;
        const float ih = 1.0f / 127.0f;
#pragma unroll 8
        for (int k = 0; k < Hc; ++k) {
            const int off = ((k >> 6) << 10) + ((((k >> 4) & 3) * 16 + bb) << 4) + (k & 15);
            s = fmaf((float)ht0[off] * ih, wl[k], s);
        }
        out[(blk * 16 + bb) * OUTc + o] = s;
    }
}

extern "C" void kernel_launch(void* const* d_in, const int* in_sizes, int n_in,
                              void* d_out, int out_size, void* d_ws, size_t ws_size,
                              hipStream_t stream) {
    const int*   inputs    = (const int*)d_in[0];
    const float* emb_table = (const float*)d_in[1];
    const float* W_ih      = (const float*)d_in[2];
    const float* W_hh      = (const float*)d_in[3];
    const float* b_ih      = (const float*)d_in[4];
    const float* b_hh      = (const float*)d_in[5];
    const float* W_lin     = (const float*)d_in[6];
    const float* b_lin     = (const float*)d_in[7];
    float* out = (float*)d_out;

    float* pe = (float*)d_ws;  // VOCAB*H*4 = 2.26 MB
    pe_kernel<<<(VOCAB + PV - 1) / PV, 256, 0, stream>>>(emb_table, W_ih, b_ih, b_hh, pe);
    rnn_mfma<<<Bc / 16, 512, 0, stream>>>(inputs, pe, W_hh, W_lin, b_lin, out);
}